// Round 13
// baseline (119.121 us; speedup 1.0000x reference)
//
#include <hip/hip_runtime.h>
#include <hip/hip_bf16.h>
#include <stdint.h>

typedef unsigned short u16;
typedef __attribute__((ext_vector_type(8))) short bf16x8;
typedef __attribute__((ext_vector_type(4))) float f32x4;
typedef __attribute__((ext_vector_type(4))) unsigned int u32x4;

// 1/sqrt(64) * log2(e): folded into Wq so softmax can use raw v_exp_f32 (exp2)
#define QSCALE 0.18033688011112042f

__device__ __forceinline__ u16 f2bf(float f) {
  return __builtin_bit_cast(u16, __float2bfloat16(f));  // native cvt, RNE
}

__device__ __forceinline__ uint32_t pkcvt(float a, float b) {
  return (uint32_t)f2bf(a) | ((uint32_t)f2bf(b) << 16);  // fuses to v_cvt_pk_bf16_f32
}

__device__ __forceinline__ void gll16(const void* g, void* l) {
  __builtin_amdgcn_global_load_lds(
      (__attribute__((address_space(1))) void*)(uintptr_t)g,
      (__attribute__((address_space(3))) void*)l, 16, 0, 0);
}

// ---------------------------------------------------------------- cvt_w
// Weight transpose+convert only (x-conversion is fused into gemm_qkv).
// 4096 blocks: 4 matrices x 1024 32x32 tiles.
__global__ __launch_bounds__(256)
void cvt_w_kernel(const float* __restrict__ Wq, const float* __restrict__ Wk,
                  const float* __restrict__ Wv, const float* __restrict__ Wo,
                  u16* __restrict__ Wqkvt, u16* __restrict__ Wot) {
  __shared__ float tile[32][33];
  const int bid = blockIdx.x, tid = threadIdx.x;
  const int z = bid >> 10, xy = bid & 1023;
  const float* src = (z == 0) ? Wq : (z == 1) ? Wk : (z == 2) ? Wv : Wo;
  const float scale = (z == 0) ? QSCALE : 1.0f;
  u16* dst = (z == 3) ? Wot : (Wqkvt + (size_t)z * 1024 * 1024);
  const int n0 = (xy & 31) * 32, k0 = (xy >> 5) * 32;
  const int tx = tid & 31, ty = tid >> 5;  // (32,8)
#pragma unroll
  for (int i = 0; i < 4; ++i)
    tile[ty * 4 + i][tx] = src[(size_t)(k0 + ty * 4 + i) * 1024 + n0 + tx];
  __syncthreads();
#pragma unroll
  for (int i = 0; i < 4; ++i)
    dst[(size_t)(n0 + ty * 4 + i) * 1024 + k0 + tx] = f2bf(tile[tx][ty * 4 + i] * scale);
}

// ---------------------------------------------------------------- gemm_qkv
// C[4096,3072] = bf16(x) @ Wqkv. A is reg-staged DIRECTLY from fp32 x with
// fused conversion (T14 issue-early / write-late): loads issued at iter top,
// pkcvt+ds_write after compute, before the barrier. B via gll16 (pre-
// transposed Wqkvt). 512 threads / 8 waves, tile 128x128, BK=64, 2-buffer,
// 128B-row swizzle ^((row&7)<<4). Same f2bf values as the old cvt_x pass ->
// bit-identical output. Q,K: [bh][n][64]. V: [bh][64][2048] PERMUTED keys.
__global__ __launch_bounds__(512, 4)
void gemm_qkv_kernel(const float* __restrict__ X, const u16* __restrict__ Bt,
                     u16* __restrict__ Qb, u16* __restrict__ Kb, u16* __restrict__ Vtb) {
  __shared__ __align__(16) u16 As[2][128 * 64];
  __shared__ __align__(16) u16 Bs[2][128 * 64];
  const int row0 = blockIdx.x * 128, col0 = blockIdx.y * 128;
  const int tid = threadIdx.x, lane = tid & 63, wid = tid >> 6;
  const int wr = (wid >> 2) * 64, wc = (wid & 3) * 32;
  const int lr = lane & 15, lg = lane >> 4;
  const int swz = (lr & 7) << 4;

  // A chunk geometry: chunk c -> row c>>3, swizzled 16B-bf16 slot; in fp32
  // source that is 8 consecutive floats at element offset sp/2.
  const int c1 = tid, c2 = tid + 512;
  const int r1 = c1 >> 3, sp1 = ((c1 & 7) * 16) ^ ((r1 & 7) << 4);
  const int r2 = c2 >> 3, sp2 = ((c2 & 7) * 16) ^ ((r2 & 7) << 4);
  const float* a1base = X + (size_t)(row0 + r1) * 1024 + sp1 / 2;
  const float* a2base = X + (size_t)(row0 + r2) * 1024 + sp2 / 2;

  f32x4 acc[4][2];
#pragma unroll
  for (int m = 0; m < 4; ++m)
#pragma unroll
    for (int n = 0; n < 2; ++n) acc[m][n] = (f32x4){0.f, 0.f, 0.f, 0.f};

  auto issueB = [&](int b, int k0) {
#pragma unroll
    for (int i = 0; i < 2; ++i) {
      const int c = tid + i * 512;
      const int row = c >> 3;
      const int sp = ((c & 7) * 16) ^ ((row & 7) << 4);
      gll16((const char*)Bt + ((size_t)(col0 + row) * 1024 + k0) * 2 + sp, (char*)Bs[b] + c * 16);
    }
  };
  auto writeA = [&](int b, const float4& p0, const float4& p1,
                    const float4& p2, const float4& p3) {
    u32x4 w;
    w.x = pkcvt(p0.x, p0.y); w.y = pkcvt(p0.z, p0.w);
    w.z = pkcvt(p1.x, p1.y); w.w = pkcvt(p1.z, p1.w);
    *(u32x4*)((char*)As[b] + c1 * 16) = w;
    w.x = pkcvt(p2.x, p2.y); w.y = pkcvt(p2.z, p2.w);
    w.z = pkcvt(p3.x, p3.y); w.w = pkcvt(p3.z, p3.w);
    *(u32x4*)((char*)As[b] + c2 * 16) = w;
  };

  // prologue: tile 0
  {
    float4 p0 = *(const float4*)(a1base);
    float4 p1 = *(const float4*)(a1base + 4);
    float4 p2 = *(const float4*)(a2base);
    float4 p3 = *(const float4*)(a2base + 4);
    issueB(0, 0);
    writeA(0, p0, p1, p2, p3);
    asm volatile("s_waitcnt vmcnt(0)" ::: "memory");
    __syncthreads();
  }

  int buf = 0;
  for (int t = 0; t < 16; ++t) {
    float4 p0, p1, p2, p3;
    if (t < 15) {  // issue next A (regs) + next B (gll16) early
      const int k0 = (t + 1) * 64;
      p0 = *(const float4*)(a1base + k0);
      p1 = *(const float4*)(a1base + k0 + 4);
      p2 = *(const float4*)(a2base + k0);
      p3 = *(const float4*)(a2base + k0 + 4);
      issueB(buf ^ 1, k0);
    }
#pragma unroll
    for (int u = 0; u < 2; ++u) {
      const int xo = (u * 64 + lg * 16) ^ swz;
      bf16x8 af[4], bfr[2];
#pragma unroll
      for (int m = 0; m < 4; ++m)
        af[m] = *(const bf16x8*)((const char*)As[buf] + (wr + m * 16 + lr) * 128 + xo);
#pragma unroll
      for (int n = 0; n < 2; ++n)
        bfr[n] = *(const bf16x8*)((const char*)Bs[buf] + (wc + n * 16 + lr) * 128 + xo);
#pragma unroll
      for (int m = 0; m < 4; ++m)
#pragma unroll
        for (int n = 0; n < 2; ++n)
          acc[m][n] = __builtin_amdgcn_mfma_f32_16x16x32_bf16(af[m], bfr[n], acc[m][n], 0, 0, 0);
    }
    if (t < 15) writeA(buf ^ 1, p0, p1, p2, p3);  // cvt+LDS-write after compute
    asm volatile("s_waitcnt vmcnt(0)" ::: "memory");
    __syncthreads();
    buf ^= 1;
  }

#pragma unroll
  for (int m = 0; m < 4; ++m) {
#pragma unroll
    for (int n = 0; n < 2; ++n) {
      const int gcol = col0 + wc + n * 16 + lr;
      const int w = gcol >> 10, rem = gcol & 1023;
      const int h = rem >> 6, dd = rem & 63;
      const int grow0 = row0 + wr + m * 16 + lg * 4;
      if (w == 2) {
        const int b0 = grow0 >> 11, nn0 = grow0 & 2047;
        const int kin = nn0 & 63;
        const int kp = (kin & 32) | ((kin & 12) << 1) | ((kin & 16) >> 2);
        ushort4 sv;
        sv.x = f2bf(acc[m][n][0]); sv.y = f2bf(acc[m][n][1]);
        sv.z = f2bf(acc[m][n][2]); sv.w = f2bf(acc[m][n][3]);
        *(ushort4*)&Vtb[((size_t)(b0 * 16 + h) * 64 + dd) * 2048 + (nn0 & ~63) + kp] = sv;
      } else {
#pragma unroll
        for (int r = 0; r < 4; ++r) {
          const int grow = grow0 + r;
          const int b = grow >> 11, nn = grow & 2047;
          const int bh = b * 16 + h;
          const u16 hv = f2bf(acc[m][n][r]);
          if (w == 0) Qb[((size_t)bh * 2048 + nn) * 64 + dd] = hv;
          else        Kb[((size_t)bh * 2048 + nn) * 64 + dd] = hv;
        }
      }
    }
  }
}

// ---------------------------------------------------------------- attn
// (unchanged from R12 — 47.5 µs proven) Flash attention, swapped operands,
// KVBLK=128, 2-buffer vmcnt(0)+barrier, phase-interleaved sub-tiles,
// fixed-shift softmax (m=8 in MFMA C-init), li via ones-MFMA, zero-shuffle
// PV, permuted-key V layout, setprio around MFMA clusters.
__global__ __launch_bounds__(256, 2)
void attn_kernel(const u16* __restrict__ Qb, const u16* __restrict__ Kb,
                 const u16* __restrict__ Vtb, u16* __restrict__ Ob) {
  __shared__ __align__(16) u16 Ks[2][128 * 64];
  __shared__ __align__(16) u16 Vs[2][128 * 64];
  const int tid = threadIdx.x, lane = tid & 63, wid = tid >> 6;
  const int bid = blockIdx.x;
  const int vv = (bid & 7) * 64 + (bid >> 3);  // XCD swizzle: 4 bh per XCD
  const int qt = vv & 15, bh = vv >> 4;
  const int lr = lane & 15, lg = lane >> 4;

  const u16* Qp = Qb + ((size_t)bh * 2048 + qt * 128 + wid * 32) * 64;
  const char* Kg = (const char*)(Kb + (size_t)bh * 2048 * 64);
  const char* Vg = (const char*)(Vtb + (size_t)bh * 64 * 2048);

  bf16x8 aq[2][2];
#pragma unroll
  for (int qc = 0; qc < 2; ++qc)
#pragma unroll
    for (int ks = 0; ks < 2; ++ks)
      aq[qc][ks] = *(const bf16x8*)&Qp[(qc * 16 + lr) * 64 + ks * 32 + lg * 8];

  auto stage = [&](int buf, int kv0) {
#pragma unroll
    for (int i = 0; i < 4; ++i) {
      const int c = tid + i * 256;
      const int row = c >> 3;
      const int sc = ((c & 7) * 16) ^ ((row & 7) << 4);
      gll16(Kg + (size_t)(kv0 + row) * 128 + sc, (char*)Ks[buf] + c * 16);
      gll16(Vg + (size_t)(row & 63) * 4096 + (size_t)(kv0 + (row >> 6) * 64) * 2 + sc,
            (char*)Vs[buf] + c * 16);
    }
  };

  const int swz = (lr & 7) << 4;
  const int xk0 = (lg * 16) ^ swz;
  const int xk1 = (64 + lg * 16) ^ swz;

  f32x4 acco[4][2];
#pragma unroll
  for (int ct = 0; ct < 4; ++ct)
#pragma unroll
    for (int qc = 0; qc < 2; ++qc) acco[ct][qc] = (f32x4){0.f, 0.f, 0.f, 0.f};
  f32x4 lacc[2];
  lacc[0] = (f32x4){0.f, 0.f, 0.f, 0.f};
  lacc[1] = (f32x4){0.f, 0.f, 0.f, 0.f};
  const f32x4 minit = (f32x4){-8.f, -8.f, -8.f, -8.f};  // fixed softmax shift
  u32x4 ow;
  ow.x = ow.y = ow.z = ow.w = 0x3F803F80u;               // bf16 1.0 pairs
  const bf16x8 ones = __builtin_bit_cast(bf16x8, ow);

  stage(0, 0);
  asm volatile("s_waitcnt vmcnt(0)" ::: "memory");
  __syncthreads();

  int buf = 0;
  for (int t = 0; t < 16; ++t) {
    if (t < 15) stage(buf ^ 1, (t + 1) * 128);
    const char* kb0 = (const char*)Ks[buf] + lr * 128;
    const char* kb1 = kb0 + 8192;
    const char* vb0 = (const char*)Vs[buf] + lr * 128;
    const char* vb1 = vb0 + 8192;

    // ---- QK(0)
    bf16x8 kf0[4][2];
#pragma unroll
    for (int kt = 0; kt < 4; ++kt) {
      kf0[kt][0] = *(const bf16x8*)(kb0 + kt * 2048 + xk0);
      kf0[kt][1] = *(const bf16x8*)(kb0 + kt * 2048 + xk1);
    }
    f32x4 s0[4][2];
    __builtin_amdgcn_s_setprio(1);
#pragma unroll
    for (int kt = 0; kt < 4; ++kt)
#pragma unroll
      for (int qc = 0; qc < 2; ++qc) {
        f32x4 tacc = __builtin_amdgcn_mfma_f32_16x16x32_bf16(kf0[kt][0], aq[qc][0], minit, 0, 0, 0);
        s0[kt][qc] = __builtin_amdgcn_mfma_f32_16x16x32_bf16(kf0[kt][1], aq[qc][1], tacc, 0, 0, 0);
      }
    __builtin_amdgcn_s_setprio(0);
    // ---- QK(1)
    bf16x8 kf1[4][2];
#pragma unroll
    for (int kt = 0; kt < 4; ++kt) {
      kf1[kt][0] = *(const bf16x8*)(kb1 + kt * 2048 + xk0);
      kf1[kt][1] = *(const bf16x8*)(kb1 + kt * 2048 + xk1);
    }
    f32x4 s1[4][2];
    __builtin_amdgcn_s_setprio(1);
#pragma unroll
    for (int kt = 0; kt < 4; ++kt)
#pragma unroll
      for (int qc = 0; qc < 2; ++qc) {
        f32x4 tacc = __builtin_amdgcn_mfma_f32_16x16x32_bf16(kf1[kt][0], aq[qc][0], minit, 0, 0, 0);
        s1[kt][qc] = __builtin_amdgcn_mfma_f32_16x16x32_bf16(kf1[kt][1], aq[qc][1], tacc, 0, 0, 0);
      }
    __builtin_amdgcn_s_setprio(0);
    // ---- V(0) fragments hoisted
    bf16x8 vf0[4][2];
#pragma unroll
    for (int ct = 0; ct < 4; ++ct)
#pragma unroll
      for (int ks = 0; ks < 2; ++ks)
        vf0[ct][ks] = *(const bf16x8*)(vb0 + ct * 2048 + ((ks * 64 + lg * 16) ^ swz));
    // ---- softmax(0) + li(0)
    bf16x8 pa0[2][2];
#pragma unroll
    for (int qc = 0; qc < 2; ++qc) {
#pragma unroll
      for (int kt = 0; kt < 4; ++kt)
#pragma unroll
        for (int r = 0; r < 4; ++r)
          s0[kt][qc][r] = __builtin_amdgcn_exp2f(s0[kt][qc][r]);
#pragma unroll
      for (int ks = 0; ks < 2; ++ks) {
        u32x4 w;
        w.x = pkcvt(s0[2 * ks][qc][0],     s0[2 * ks][qc][1]);
        w.y = pkcvt(s0[2 * ks][qc][2],     s0[2 * ks][qc][3]);
        w.z = pkcvt(s0[2 * ks + 1][qc][0], s0[2 * ks + 1][qc][1]);
        w.w = pkcvt(s0[2 * ks + 1][qc][2], s0[2 * ks + 1][qc][3]);
        pa0[qc][ks] = __builtin_bit_cast(bf16x8, w);
      }
      lacc[qc] = __builtin_amdgcn_mfma_f32_16x16x32_bf16(ones, pa0[qc][0], lacc[qc], 0, 0, 0);
      lacc[qc] = __builtin_amdgcn_mfma_f32_16x16x32_bf16(ones, pa0[qc][1], lacc[qc], 0, 0, 0);
    }
    // ---- PV(0)
    __builtin_amdgcn_s_setprio(1);
#pragma unroll
    for (int ct = 0; ct < 4; ++ct)
#pragma unroll
      for (int ks = 0; ks < 2; ++ks)
#pragma unroll
        for (int qc = 0; qc < 2; ++qc)
          acco[ct][qc] = __builtin_amdgcn_mfma_f32_16x16x32_bf16(vf0[ct][ks], pa0[qc][ks], acco[ct][qc], 0, 0, 0);
    __builtin_amdgcn_s_setprio(0);
    // ---- V(1) fragments
    bf16x8 vf1[4][2];
#pragma unroll
    for (int ct = 0; ct < 4; ++ct)
#pragma unroll
      for (int ks = 0; ks < 2; ++ks)
        vf1[ct][ks] = *(const bf16x8*)(vb1 + ct * 2048 + ((ks * 64 + lg * 16) ^ swz));
    // ---- softmax(1) + li(1)
    bf16x8 pa1[2][2];
#pragma unroll
    for (int qc = 0; qc < 2; ++qc) {
#pragma unroll
      for (int kt = 0; kt < 4; ++kt)
#pragma unroll
        for (int r = 0; r < 4; ++r)
          s1[kt][qc][r] = __builtin_amdgcn_exp2f(s1[kt][qc][r]);
#pragma unroll
      for (int ks = 0; ks < 2; ++ks) {
        u32x4 w;
        w.x = pkcvt(s1[2 * ks][qc][0],     s1[2 * ks][qc][1]);
        w.y = pkcvt(s1[2 * ks][qc][2],     s1[2 * ks][qc][3]);
        w.z = pkcvt(s1[2 * ks + 1][qc][0], s1[2 * ks + 1][qc][1]);
        w.w = pkcvt(s1[2 * ks + 1][qc][2], s1[2 * ks + 1][qc][3]);
        pa1[qc][ks] = __builtin_bit_cast(bf16x8, w);
      }
      lacc[qc] = __builtin_amdgcn_mfma_f32_16x16x32_bf16(ones, pa1[qc][0], lacc[qc], 0, 0, 0);
      lacc[qc] = __builtin_amdgcn_mfma_f32_16x16x32_bf16(ones, pa1[qc][1], lacc[qc], 0, 0, 0);
    }
    // ---- PV(1)
    __builtin_amdgcn_s_setprio(1);
#pragma unroll
    for (int ct = 0; ct < 4; ++ct)
#pragma unroll
      for (int ks = 0; ks < 2; ++ks)
#pragma unroll
        for (int qc = 0; qc < 2; ++qc)
          acco[ct][qc] = __builtin_amdgcn_mfma_f32_16x16x32_bf16(vf1[ct][ks], pa1[qc][ks], acco[ct][qc], 0, 0, 0);
    __builtin_amdgcn_s_setprio(0);

    asm volatile("s_waitcnt vmcnt(0)" ::: "memory");
    __syncthreads();
    buf ^= 1;
  }

  // epilogue: lane owns q = qc*16+lr; d = ct*16 + lg*4 + r
  const int b = bh >> 4, h = bh & 15;
#pragma unroll
  for (int qc = 0; qc < 2; ++qc) {
    const int q = qt * 128 + wid * 32 + qc * 16 + lr;
    const float inv = 1.0f / lacc[qc][0];
#pragma unroll
    for (int ct = 0; ct < 4; ++ct) {
      uint2 st;
      st.x = pkcvt(acco[ct][qc][0] * inv, acco[ct][qc][1] * inv);
      st.y = pkcvt(acco[ct][qc][2] * inv, acco[ct][qc][3] * inv);
      *(uint2*)&Ob[((size_t)b * 2048 + q) * 1024 + h * 64 + ct * 16 + lg * 4] = st;
    }
  }
}

// ---------------------------------------------------------------- gemm_out
// (unchanged from R12) out[4096,1024] = Ob @ Wo + bo. Tile 64x128, 512
// threads / 8 waves, BK=64 2-buffer.
__global__ __launch_bounds__(512, 4)
void gemm_out_kernel(const u16* __restrict__ A, const u16* __restrict__ Bt,
                     const float* __restrict__ bo, float* __restrict__ out) {
  __shared__ __align__(16) u16 As[2][64 * 64];
  __shared__ __align__(16) u16 Bs[2][128 * 64];
  const int row0 = blockIdx.x * 64, col0 = blockIdx.y * 128;
  const int tid = threadIdx.x, lane = tid & 63, wid = tid >> 6;
  const int wr = (wid >> 2) * 32, wc = (wid & 3) * 32;
  const int lr = lane & 15, lg = lane >> 4;
  const int swz = (lr & 7) << 4;

  f32x4 acc[2][2];
#pragma unroll
  for (int m = 0; m < 2; ++m)
#pragma unroll
    for (int n = 0; n < 2; ++n) acc[m][n] = (f32x4){0.f, 0.f, 0.f, 0.f};

  auto stage = [&](int b, int k0) {
    {
      const int c = tid;
      const int row = c >> 3;
      const int sp = ((c & 7) * 16) ^ ((row & 7) << 4);
      gll16((const char*)A + ((size_t)(row0 + row) * 1024 + k0) * 2 + sp, (char*)As[b] + c * 16);
    }
#pragma unroll
    for (int i = 0; i < 2; ++i) {
      const int c = tid + i * 512;
      const int row = c >> 3;
      const int sp = ((c & 7) * 16) ^ ((row & 7) << 4);
      gll16((const char*)Bt + ((size_t)(col0 + row) * 1024 + k0) * 2 + sp, (char*)Bs[b] + c * 16);
    }
  };

  stage(0, 0);
  asm volatile("s_waitcnt vmcnt(0)" ::: "memory");
  __syncthreads();

  int buf = 0;
  for (int t = 0; t < 16; ++t) {
    if (t < 15) stage(buf ^ 1, (t + 1) * 64);
#pragma unroll
    for (int u = 0; u < 2; ++u) {
      const int xo = (u * 64 + lg * 16) ^ swz;
      bf16x8 af[2], bfr[2];
#pragma unroll
      for (int m = 0; m < 2; ++m)
        af[m] = *(const bf16x8*)((const char*)As[buf] + (wr + m * 16 + lr) * 128 + xo);
#pragma unroll
      for (int n = 0; n < 2; ++n)
        bfr[n] = *(const bf16x8*)((const char*)Bs[buf] + (wc + n * 16 + lr) * 128 + xo);
#pragma unroll
      for (int m = 0; m < 2; ++m)
#pragma unroll
        for (int n = 0; n < 2; ++n)
          acc[m][n] = __builtin_amdgcn_mfma_f32_16x16x32_bf16(af[m], bfr[n], acc[m][n], 0, 0, 0);
    }
    asm volatile("s_waitcnt vmcnt(0)" ::: "memory");
    __syncthreads();
    buf ^= 1;
  }

#pragma unroll
  for (int m = 0; m < 2; ++m) {
#pragma unroll
    for (int n = 0; n < 2; ++n) {
      const int gcol = col0 + wc + n * 16 + lr;
      const float bv = bo[gcol];
#pragma unroll
      for (int r = 0; r < 4; ++r) {
        const int grow = row0 + wr + m * 16 + lg * 4 + r;
        out[(size_t)grow * 1024 + gcol] = acc[m][n][r] + bv;
      }
    }
  }
}

// ---------------------------------------------------------------- launch
extern "C" void kernel_launch(void* const* d_in, const int* in_sizes, int n_in,
                              void* d_out, int out_size, void* d_ws, size_t ws_size,
                              hipStream_t stream) {
  const float* x  = (const float*)d_in[0];
  const float* Wq = (const float*)d_in[1];
  const float* Wk = (const float*)d_in[2];
  const float* Wv = (const float*)d_in[3];
  const float* Wo = (const float*)d_in[4];
  const float* bo = (const float*)d_in[5];
  float* out = (float*)d_out;

  char* ws = (char*)d_ws;
  u16* Ob    = (u16*)(ws);                          // 8 MB  [4096][1024] (attn out)
  u16* wqkvt = (u16*)(ws + ((size_t)8  << 20));     // 6 MB  [3072][1024]
  u16* wot   = (u16*)(ws + ((size_t)14 << 20));     // 2 MB  [1024][1024]
  u16* Qb    = (u16*)(ws + ((size_t)16 << 20));     // 8 MB  [32][2048][64]
  u16* Kb    = (u16*)(ws + ((size_t)24 << 20));     // 8 MB  [32][2048][64]
  u16* Vtb   = (u16*)(ws + ((size_t)32 << 20));     // 8 MB  [32][64][2048] (permuted keys)

  hipLaunchKernelGGL(cvt_w_kernel, dim3(4096), dim3(256), 0, stream,
                     Wq, Wk, Wv, Wo, wqkvt, wot);
  hipLaunchKernelGGL(gemm_qkv_kernel, dim3(32, 24), dim3(512), 0, stream,
                     x, wqkvt, Qb, Kb, Vtb);
  hipLaunchKernelGGL(attn_kernel, dim3(512), dim3(256), 0, stream,
                     Qb, Kb, Vtb, Ob);
  hipLaunchKernelGGL(gemm_out_kernel, dim3(64, 8), dim3(512), 0, stream,
                     Ob, wot, bo, out);
}

// Round 14
// 107.176 us; speedup vs baseline: 1.1114x; 1.1114x over previous
//
#include <hip/hip_runtime.h>
#include <hip/hip_bf16.h>
#include <stdint.h>

typedef unsigned short u16;
typedef __attribute__((ext_vector_type(8))) short bf16x8;
typedef __attribute__((ext_vector_type(4))) float f32x4;
typedef __attribute__((ext_vector_type(4))) unsigned int u32x4;

// 1/sqrt(64) * log2(e): folded into Wq so softmax can use raw v_exp_f32 (exp2)
#define QSCALE 0.18033688011112042f

__device__ __forceinline__ u16 f2bf(float f) {
  return __builtin_bit_cast(u16, __float2bfloat16(f));  // native cvt, RNE
}

__device__ __forceinline__ uint32_t pkcvt(float a, float b) {
  return (uint32_t)f2bf(a) | ((uint32_t)f2bf(b) << 16);  // fuses to v_cvt_pk_bf16_f32
}

__device__ __forceinline__ void gll16(const void* g, void* l) {
  __builtin_amdgcn_global_load_lds(
      (__attribute__((address_space(1))) void*)(uintptr_t)g,
      (__attribute__((address_space(3))) void*)l, 16, 0, 0);
}

// ---------------------------------------------------------------- cvt_all
// blocks [0,4096): weight transpose+convert; [4096,6144): x fp32 -> bf16.
// (x pre-converted ONCE: xb is re-read 24x by gemm_qkv col-tiles — fusing
// the convert into the GEMM un-amortizes it, R13 regression.)
__global__ __launch_bounds__(256)
void cvt_all_kernel(const float* __restrict__ x,
                    const float* __restrict__ Wq, const float* __restrict__ Wk,
                    const float* __restrict__ Wv, const float* __restrict__ Wo,
                    u16* __restrict__ xb, u16* __restrict__ Wqkvt, u16* __restrict__ Wot) {
  __shared__ float tile[32][33];
  const int bid = blockIdx.x, tid = threadIdx.x;
  if (bid < 4096) {
    const int z = bid >> 10, xy = bid & 1023;
    const float* src = (z == 0) ? Wq : (z == 1) ? Wk : (z == 2) ? Wv : Wo;
    const float scale = (z == 0) ? QSCALE : 1.0f;
    u16* dst = (z == 3) ? Wot : (Wqkvt + (size_t)z * 1024 * 1024);
    const int n0 = (xy & 31) * 32, k0 = (xy >> 5) * 32;
    const int tx = tid & 31, ty = tid >> 5;  // (32,8)
#pragma unroll
    for (int i = 0; i < 4; ++i)
      tile[ty * 4 + i][tx] = src[(size_t)(k0 + ty * 4 + i) * 1024 + n0 + tx];
    __syncthreads();
#pragma unroll
    for (int i = 0; i < 4; ++i)
      dst[(size_t)(n0 + ty * 4 + i) * 1024 + k0 + tx] = f2bf(tile[tx][ty * 4 + i] * scale);
  } else {
    size_t i = (size_t)(bid - 4096) * 256 + tid;
    const float4* p = (const float4*)x + i * 2;
    float4 a = p[0], b = p[1];
    ushort4 lo, hi;
    lo.x = f2bf(a.x); lo.y = f2bf(a.y); lo.z = f2bf(a.z); lo.w = f2bf(a.w);
    hi.x = f2bf(b.x); hi.y = f2bf(b.y); hi.z = f2bf(b.z); hi.w = f2bf(b.w);
    ((ushort4*)xb)[i * 2]     = lo;
    ((ushort4*)xb)[i * 2 + 1] = hi;
  }
}

// ---------------------------------------------------------------- gemm_qkv
// C[4096,3072] = xb @ Wqkv (Bt pre-transposed). 512 threads / 8 waves, tile
// 128x128, BK=64 2-buffer, gll16 staging with 128B-row swizzle ^((row&7)<<4).
// Q,K: [bh][n][64]. V: [bh][64][2048] PERMUTED keys (pi(k)=ks*32+lg*8+jg*4+r).
__global__ __launch_bounds__(512, 4)
void gemm_qkv_kernel(const u16* __restrict__ A, const u16* __restrict__ Bt,
                     u16* __restrict__ Qb, u16* __restrict__ Kb, u16* __restrict__ Vtb) {
  __shared__ __align__(16) u16 As[2][128 * 64];
  __shared__ __align__(16) u16 Bs[2][128 * 64];
  const int row0 = blockIdx.x * 128, col0 = blockIdx.y * 128;
  const int tid = threadIdx.x, lane = tid & 63, wid = tid >> 6;
  const int wr = (wid >> 2) * 64, wc = (wid & 3) * 32;
  const int lr = lane & 15, lg = lane >> 4;
  const int swz = (lr & 7) << 4;

  f32x4 acc[4][2];
#pragma unroll
  for (int m = 0; m < 4; ++m)
#pragma unroll
    for (int n = 0; n < 2; ++n) acc[m][n] = (f32x4){0.f, 0.f, 0.f, 0.f};

  auto stage = [&](int b, int k0) {
#pragma unroll
    for (int i = 0; i < 2; ++i) {
      const int c = tid + i * 512;
      const int row = c >> 3;
      const int sp = ((c & 7) * 16) ^ ((row & 7) << 4);
      gll16((const char*)A  + ((size_t)(row0 + row) * 1024 + k0) * 2 + sp, (char*)As[b] + c * 16);
      gll16((const char*)Bt + ((size_t)(col0 + row) * 1024 + k0) * 2 + sp, (char*)Bs[b] + c * 16);
    }
  };

  stage(0, 0);
  asm volatile("s_waitcnt vmcnt(0)" ::: "memory");
  __syncthreads();

  int buf = 0;
  for (int t = 0; t < 16; ++t) {
    if (t < 15) stage(buf ^ 1, (t + 1) * 64);
#pragma unroll
    for (int u = 0; u < 2; ++u) {
      const int xo = (u * 64 + lg * 16) ^ swz;
      bf16x8 af[4], bfr[2];
#pragma unroll
      for (int m = 0; m < 4; ++m)
        af[m] = *(const bf16x8*)((const char*)As[buf] + (wr + m * 16 + lr) * 128 + xo);
#pragma unroll
      for (int n = 0; n < 2; ++n)
        bfr[n] = *(const bf16x8*)((const char*)Bs[buf] + (wc + n * 16 + lr) * 128 + xo);
#pragma unroll
      for (int m = 0; m < 4; ++m)
#pragma unroll
        for (int n = 0; n < 2; ++n)
          acc[m][n] = __builtin_amdgcn_mfma_f32_16x16x32_bf16(af[m], bfr[n], acc[m][n], 0, 0, 0);
    }
    asm volatile("s_waitcnt vmcnt(0)" ::: "memory");
    __syncthreads();
    buf ^= 1;
  }

#pragma unroll
  for (int m = 0; m < 4; ++m) {
#pragma unroll
    for (int n = 0; n < 2; ++n) {
      const int gcol = col0 + wc + n * 16 + lr;
      const int w = gcol >> 10, rem = gcol & 1023;
      const int h = rem >> 6, dd = rem & 63;
      const int grow0 = row0 + wr + m * 16 + lg * 4;
      if (w == 2) {
        const int b0 = grow0 >> 11, nn0 = grow0 & 2047;
        const int kin = nn0 & 63;
        const int kp = (kin & 32) | ((kin & 12) << 1) | ((kin & 16) >> 2);
        ushort4 sv;
        sv.x = f2bf(acc[m][n][0]); sv.y = f2bf(acc[m][n][1]);
        sv.z = f2bf(acc[m][n][2]); sv.w = f2bf(acc[m][n][3]);
        *(ushort4*)&Vtb[((size_t)(b0 * 16 + h) * 64 + dd) * 2048 + (nn0 & ~63) + kp] = sv;
      } else {
#pragma unroll
        for (int r = 0; r < 4; ++r) {
          const int grow = grow0 + r;
          const int b = grow >> 11, nn = grow & 2047;
          const int bh = b * 16 + h;
          const u16 hv = f2bf(acc[m][n][r]);
          if (w == 0) Qb[((size_t)bh * 2048 + nn) * 64 + dd] = hv;
          else        Kb[((size_t)bh * 2048 + nn) * 64 + dd] = hv;
        }
      }
    }
  }
}

// ---------------------------------------------------------------- attn
// Flash attention, swapped operands, KVBLK=128, 2-buffer vmcnt(0)+barrier,
// phase-interleaved sub-tiles (QK0,QK1,exp0,PV0,exp1,PV1), fixed-shift
// softmax (m=8 in MFMA C-init), li via ones-MFMA, zero-shuffle PV,
// permuted-key V layout, setprio around MFMA clusters.
__global__ __launch_bounds__(256, 2)
void attn_kernel(const u16* __restrict__ Qb, const u16* __restrict__ Kb,
                 const u16* __restrict__ Vtb, u16* __restrict__ Ob) {
  __shared__ __align__(16) u16 Ks[2][128 * 64];
  __shared__ __align__(16) u16 Vs[2][128 * 64];
  const int tid = threadIdx.x, lane = tid & 63, wid = tid >> 6;
  const int bid = blockIdx.x;
  const int vv = (bid & 7) * 64 + (bid >> 3);  // XCD swizzle: 4 bh per XCD
  const int qt = vv & 15, bh = vv >> 4;
  const int lr = lane & 15, lg = lane >> 4;

  const u16* Qp = Qb + ((size_t)bh * 2048 + qt * 128 + wid * 32) * 64;
  const char* Kg = (const char*)(Kb + (size_t)bh * 2048 * 64);
  const char* Vg = (const char*)(Vtb + (size_t)bh * 64 * 2048);

  bf16x8 aq[2][2];
#pragma unroll
  for (int qc = 0; qc < 2; ++qc)
#pragma unroll
    for (int ks = 0; ks < 2; ++ks)
      aq[qc][ks] = *(const bf16x8*)&Qp[(qc * 16 + lr) * 64 + ks * 32 + lg * 8];

  auto stage = [&](int buf, int kv0) {
#pragma unroll
    for (int i = 0; i < 4; ++i) {
      const int c = tid + i * 256;
      const int row = c >> 3;
      const int sc = ((c & 7) * 16) ^ ((row & 7) << 4);
      gll16(Kg + (size_t)(kv0 + row) * 128 + sc, (char*)Ks[buf] + c * 16);
      gll16(Vg + (size_t)(row & 63) * 4096 + (size_t)(kv0 + (row >> 6) * 64) * 2 + sc,
            (char*)Vs[buf] + c * 16);
    }
  };

  const int swz = (lr & 7) << 4;
  const int xk0 = (lg * 16) ^ swz;
  const int xk1 = (64 + lg * 16) ^ swz;

  f32x4 acco[4][2];
#pragma unroll
  for (int ct = 0; ct < 4; ++ct)
#pragma unroll
    for (int qc = 0; qc < 2; ++qc) acco[ct][qc] = (f32x4){0.f, 0.f, 0.f, 0.f};
  f32x4 lacc[2];
  lacc[0] = (f32x4){0.f, 0.f, 0.f, 0.f};
  lacc[1] = (f32x4){0.f, 0.f, 0.f, 0.f};
  const f32x4 minit = (f32x4){-8.f, -8.f, -8.f, -8.f};  // fixed softmax shift
  u32x4 ow;
  ow.x = ow.y = ow.z = ow.w = 0x3F803F80u;               // bf16 1.0 pairs
  const bf16x8 ones = __builtin_bit_cast(bf16x8, ow);

  stage(0, 0);
  asm volatile("s_waitcnt vmcnt(0)" ::: "memory");
  __syncthreads();

  int buf = 0;
  for (int t = 0; t < 16; ++t) {
    if (t < 15) stage(buf ^ 1, (t + 1) * 128);
    const char* kb0 = (const char*)Ks[buf] + lr * 128;
    const char* kb1 = kb0 + 8192;
    const char* vb0 = (const char*)Vs[buf] + lr * 128;
    const char* vb1 = vb0 + 8192;

    // ---- QK(0)
    bf16x8 kf0[4][2];
#pragma unroll
    for (int kt = 0; kt < 4; ++kt) {
      kf0[kt][0] = *(const bf16x8*)(kb0 + kt * 2048 + xk0);
      kf0[kt][1] = *(const bf16x8*)(kb0 + kt * 2048 + xk1);
    }
    f32x4 s0[4][2];
    __builtin_amdgcn_s_setprio(1);
#pragma unroll
    for (int kt = 0; kt < 4; ++kt)
#pragma unroll
      for (int qc = 0; qc < 2; ++qc) {
        f32x4 tacc = __builtin_amdgcn_mfma_f32_16x16x32_bf16(kf0[kt][0], aq[qc][0], minit, 0, 0, 0);
        s0[kt][qc] = __builtin_amdgcn_mfma_f32_16x16x32_bf16(kf0[kt][1], aq[qc][1], tacc, 0, 0, 0);
      }
    __builtin_amdgcn_s_setprio(0);
    // ---- QK(1)
    bf16x8 kf1[4][2];
#pragma unroll
    for (int kt = 0; kt < 4; ++kt) {
      kf1[kt][0] = *(const bf16x8*)(kb1 + kt * 2048 + xk0);
      kf1[kt][1] = *(const bf16x8*)(kb1 + kt * 2048 + xk1);
    }
    f32x4 s1[4][2];
    __builtin_amdgcn_s_setprio(1);
#pragma unroll
    for (int kt = 0; kt < 4; ++kt)
#pragma unroll
      for (int qc = 0; qc < 2; ++qc) {
        f32x4 tacc = __builtin_amdgcn_mfma_f32_16x16x32_bf16(kf1[kt][0], aq[qc][0], minit, 0, 0, 0);
        s1[kt][qc] = __builtin_amdgcn_mfma_f32_16x16x32_bf16(kf1[kt][1], aq[qc][1], tacc, 0, 0, 0);
      }
    __builtin_amdgcn_s_setprio(0);
    // ---- V(0) fragments hoisted
    bf16x8 vf0[4][2];
#pragma unroll
    for (int ct = 0; ct < 4; ++ct)
#pragma unroll
      for (int ks = 0; ks < 2; ++ks)
        vf0[ct][ks] = *(const bf16x8*)(vb0 + ct * 2048 + ((ks * 64 + lg * 16) ^ swz));
    // ---- softmax(0) + li(0)
    bf16x8 pa0[2][2];
#pragma unroll
    for (int qc = 0; qc < 2; ++qc) {
#pragma unroll
      for (int kt = 0; kt < 4; ++kt)
#pragma unroll
        for (int r = 0; r < 4; ++r)
          s0[kt][qc][r] = __builtin_amdgcn_exp2f(s0[kt][qc][r]);
#pragma unroll
      for (int ks = 0; ks < 2; ++ks) {
        u32x4 w;
        w.x = pkcvt(s0[2 * ks][qc][0],     s0[2 * ks][qc][1]);
        w.y = pkcvt(s0[2 * ks][qc][2],     s0[2 * ks][qc][3]);
        w.z = pkcvt(s0[2 * ks + 1][qc][0], s0[2 * ks + 1][qc][1]);
        w.w = pkcvt(s0[2 * ks + 1][qc][2], s0[2 * ks + 1][qc][3]);
        pa0[qc][ks] = __builtin_bit_cast(bf16x8, w);
      }
      lacc[qc] = __builtin_amdgcn_mfma_f32_16x16x32_bf16(ones, pa0[qc][0], lacc[qc], 0, 0, 0);
      lacc[qc] = __builtin_amdgcn_mfma_f32_16x16x32_bf16(ones, pa0[qc][1], lacc[qc], 0, 0, 0);
    }
    // ---- PV(0)
    __builtin_amdgcn_s_setprio(1);
#pragma unroll
    for (int ct = 0; ct < 4; ++ct)
#pragma unroll
      for (int ks = 0; ks < 2; ++ks)
#pragma unroll
        for (int qc = 0; qc < 2; ++qc)
          acco[ct][qc] = __builtin_amdgcn_mfma_f32_16x16x32_bf16(vf0[ct][ks], pa0[qc][ks], acco[ct][qc], 0, 0, 0);
    __builtin_amdgcn_s_setprio(0);
    // ---- V(1) fragments
    bf16x8 vf1[4][2];
#pragma unroll
    for (int ct = 0; ct < 4; ++ct)
#pragma unroll
      for (int ks = 0; ks < 2; ++ks)
        vf1[ct][ks] = *(const bf16x8*)(vb1 + ct * 2048 + ((ks * 64 + lg * 16) ^ swz));
    // ---- softmax(1) + li(1)
    bf16x8 pa1[2][2];
#pragma unroll
    for (int qc = 0; qc < 2; ++qc) {
#pragma unroll
      for (int kt = 0; kt < 4; ++kt)
#pragma unroll
        for (int r = 0; r < 4; ++r)
          s1[kt][qc][r] = __builtin_amdgcn_exp2f(s1[kt][qc][r]);
#pragma unroll
      for (int ks = 0; ks < 2; ++ks) {
        u32x4 w;
        w.x = pkcvt(s1[2 * ks][qc][0],     s1[2 * ks][qc][1]);
        w.y = pkcvt(s1[2 * ks][qc][2],     s1[2 * ks][qc][3]);
        w.z = pkcvt(s1[2 * ks + 1][qc][0], s1[2 * ks + 1][qc][1]);
        w.w = pkcvt(s1[2 * ks + 1][qc][2], s1[2 * ks + 1][qc][3]);
        pa1[qc][ks] = __builtin_bit_cast(bf16x8, w);
      }
      lacc[qc] = __builtin_amdgcn_mfma_f32_16x16x32_bf16(ones, pa1[qc][0], lacc[qc], 0, 0, 0);
      lacc[qc] = __builtin_amdgcn_mfma_f32_16x16x32_bf16(ones, pa1[qc][1], lacc[qc], 0, 0, 0);
    }
    // ---- PV(1)
    __builtin_amdgcn_s_setprio(1);
#pragma unroll
    for (int ct = 0; ct < 4; ++ct)
#pragma unroll
      for (int ks = 0; ks < 2; ++ks)
#pragma unroll
        for (int qc = 0; qc < 2; ++qc)
          acco[ct][qc] = __builtin_amdgcn_mfma_f32_16x16x32_bf16(vf1[ct][ks], pa1[qc][ks], acco[ct][qc], 0, 0, 0);
    __builtin_amdgcn_s_setprio(0);

    asm volatile("s_waitcnt vmcnt(0)" ::: "memory");
    __syncthreads();
    buf ^= 1;
  }

  // epilogue: lane owns q = qc*16+lr; d = ct*16 + lg*4 + r
  const int b = bh >> 4, h = bh & 15;
#pragma unroll
  for (int qc = 0; qc < 2; ++qc) {
    const int q = qt * 128 + wid * 32 + qc * 16 + lr;
    const float inv = 1.0f / lacc[qc][0];
#pragma unroll
    for (int ct = 0; ct < 4; ++ct) {
      uint2 st;
      st.x = pkcvt(acco[ct][qc][0] * inv, acco[ct][qc][1] * inv);
      st.y = pkcvt(acco[ct][qc][2] * inv, acco[ct][qc][3] * inv);
      *(uint2*)&Ob[((size_t)b * 2048 + q) * 1024 + h * 64 + ct * 16 + lg * 4] = st;
    }
  }
}

// ---------------------------------------------------------------- gemm_out
// out[4096,1024] = Ob @ Wo + bo. Tile 64x128 (grid 512 = 2 blocks/CU),
// 512 threads / 8 waves, BK=64 2-buffer.
__global__ __launch_bounds__(512, 4)
void gemm_out_kernel(const u16* __restrict__ A, const u16* __restrict__ Bt,
                     const float* __restrict__ bo, float* __restrict__ out) {
  __shared__ __align__(16) u16 As[2][64 * 64];
  __shared__ __align__(16) u16 Bs[2][128 * 64];
  const int row0 = blockIdx.x * 64, col0 = blockIdx.y * 128;
  const int tid = threadIdx.x, lane = tid & 63, wid = tid >> 6;
  const int wr = (wid >> 2) * 32, wc = (wid & 3) * 32;
  const int lr = lane & 15, lg = lane >> 4;
  const int swz = (lr & 7) << 4;

  f32x4 acc[2][2];
#pragma unroll
  for (int m = 0; m < 2; ++m)
#pragma unroll
    for (int n = 0; n < 2; ++n) acc[m][n] = (f32x4){0.f, 0.f, 0.f, 0.f};

  auto stage = [&](int b, int k0) {
    {
      const int c = tid;
      const int row = c >> 3;
      const int sp = ((c & 7) * 16) ^ ((row & 7) << 4);
      gll16((const char*)A + ((size_t)(row0 + row) * 1024 + k0) * 2 + sp, (char*)As[b] + c * 16);
    }
#pragma unroll
    for (int i = 0; i < 2; ++i) {
      const int c = tid + i * 512;
      const int row = c >> 3;
      const int sp = ((c & 7) * 16) ^ ((row & 7) << 4);
      gll16((const char*)Bt + ((size_t)(col0 + row) * 1024 + k0) * 2 + sp, (char*)Bs[b] + c * 16);
    }
  };

  stage(0, 0);
  asm volatile("s_waitcnt vmcnt(0)" ::: "memory");
  __syncthreads();

  int buf = 0;
  for (int t = 0; t < 16; ++t) {
    if (t < 15) stage(buf ^ 1, (t + 1) * 64);
#pragma unroll
    for (int u = 0; u < 2; ++u) {
      const int xo = (u * 64 + lg * 16) ^ swz;
      bf16x8 af[2], bfr[2];
#pragma unroll
      for (int m = 0; m < 2; ++m)
        af[m] = *(const bf16x8*)((const char*)As[buf] + (wr + m * 16 + lr) * 128 + xo);
#pragma unroll
      for (int n = 0; n < 2; ++n)
        bfr[n] = *(const bf16x8*)((const char*)Bs[buf] + (wc + n * 16 + lr) * 128 + xo);
#pragma unroll
      for (int m = 0; m < 2; ++m)
#pragma unroll
        for (int n = 0; n < 2; ++n)
          acc[m][n] = __builtin_amdgcn_mfma_f32_16x16x32_bf16(af[m], bfr[n], acc[m][n], 0, 0, 0);
    }
    asm volatile("s_waitcnt vmcnt(0)" ::: "memory");
    __syncthreads();
    buf ^= 1;
  }

#pragma unroll
  for (int m = 0; m < 2; ++m) {
#pragma unroll
    for (int n = 0; n < 2; ++n) {
      const int gcol = col0 + wc + n * 16 + lr;
      const float bv = bo[gcol];
#pragma unroll
      for (int r = 0; r < 4; ++r) {
        const int grow = row0 + wr + m * 16 + lg * 4 + r;
        out[(size_t)grow * 1024 + gcol] = acc[m][n][r] + bv;
      }
    }
  }
}

// ---------------------------------------------------------------- launch
extern "C" void kernel_launch(void* const* d_in, const int* in_sizes, int n_in,
                              void* d_out, int out_size, void* d_ws, size_t ws_size,
                              hipStream_t stream) {
  const float* x  = (const float*)d_in[0];
  const float* Wq = (const float*)d_in[1];
  const float* Wk = (const float*)d_in[2];
  const float* Wv = (const float*)d_in[3];
  const float* Wo = (const float*)d_in[4];
  const float* bo = (const float*)d_in[5];
  float* out = (float*)d_out;

  char* ws = (char*)d_ws;
  u16* xb    = (u16*)(ws);                          // 8 MB  [4096][1024]
  u16* wqkvt = (u16*)(ws + ((size_t)8  << 20));     // 6 MB  [3072][1024]
  u16* wot   = (u16*)(ws + ((size_t)14 << 20));     // 2 MB  [1024][1024]
  u16* Qb    = (u16*)(ws + ((size_t)16 << 20));     // 8 MB  [32][2048][64]
  u16* Kb    = (u16*)(ws + ((size_t)24 << 20));     // 8 MB  [32][2048][64]
  u16* Vtb   = (u16*)(ws + ((size_t)32 << 20));     // 8 MB  [32][64][2048] (permuted keys)
  u16* Ob    = xb;  // alias: xb's last reader (gemm_qkv) precedes attn

  hipLaunchKernelGGL(cvt_all_kernel, dim3(6144), dim3(256), 0, stream,
                     x, Wq, Wk, Wv, Wo, xb, wqkvt, wot);
  hipLaunchKernelGGL(gemm_qkv_kernel, dim3(32, 24), dim3(512), 0, stream,
                     xb, wqkvt, Qb, Kb, Vtb);
  hipLaunchKernelGGL(attn_kernel, dim3(512), dim3(256), 0, stream,
                     Qb, Kb, Vtb, Ob);
  hipLaunchKernelGGL(gemm_out_kernel, dim3(64, 8), dim3(512), 0, stream,
                     Ob, wot, bo, out);
}